// Round 7
// baseline (394.864 us; speedup 1.0000x reference)
//
#include <hip/hip_runtime.h>

#define D 128
#define SCAN_CHUNK 1024   // elements per scan block (256 threads x int4)
#define NSLICE 8          // XCD count: blockIdx%8 -> XCD (perf heuristic)
#define LDSPITCH 136      // ushorts/row: 128+8 pad (272B = 68 words, 68%32=4 -> 2-way=free)

typedef __attribute__((ext_vector_type(8))) short bf16x8;   // 8 bf16 = 4 VGPR
typedef __attribute__((ext_vector_type(4))) float f32x4;    // MFMA acc

__device__ __forceinline__ unsigned short f2bf(float f) {   // fp32 -> bf16 RNE
    union { float f; unsigned int u; } c; c.f = f;
    return (unsigned short)((c.u + 0x7FFFu + ((c.u >> 16) & 1u)) >> 16);
}

// ---------------------------------------------------------------------------
// x (fp32) -> xb (bf16) for the gather.
// ---------------------------------------------------------------------------
__global__ __launch_bounds__(256) void convert_kernel(
    const float* __restrict__ x, unsigned short* __restrict__ xb, int total4)
{
    int gid = blockIdx.x * 256 + threadIdx.x;
    if (gid >= total4) return;
    float4 v = ((const float4*)x)[gid];
    ushort4 o;
    o.x = f2bf(v.x); o.y = f2bf(v.y); o.z = f2bf(v.z); o.w = f2bf(v.w);
    ((ushort4*)xb)[gid] = o;
}

// ---------------------------------------------------------------------------
// W [k][n] fp32 -> Wt [n][k] bf16 (transposed so B-frags are 16B-contiguous).
// ---------------------------------------------------------------------------
__global__ __launch_bounds__(256) void convw_kernel(
    const float* __restrict__ W, unsigned short* __restrict__ Wt)
{
    int gid = blockIdx.x * 256 + threadIdx.x;   // 0..16383
    int n = gid >> 7, k = gid & 127;
    Wt[n * 128 + k] = f2bf(W[k * 128 + n]);
}

// ---------------------------------------------------------------------------
// CSR step 1: degree histogram, XCD-sliced.  ei stream read non-temporally
// so the 6.4 MB dst stream doesn't evict the slice's deg lines from L2.
// ---------------------------------------------------------------------------
__global__ __launch_bounds__(256) void hist_kernel(
    const int* __restrict__ ei, int* __restrict__ deg, int E, int sliceSize)
{
    int slice = blockIdx.x & (NSLICE - 1);
    int gid = (blockIdx.x >> 3) * 256 + threadIdx.x;
    if (gid >= E) return;
    int d = __builtin_nontemporal_load(&ei[E + gid]);
    int lo = slice * sliceSize;
    if (d < lo || d >= lo + sliceSize) return;
    atomicAdd(&deg[d], 1);
}

// ---------------------------------------------------------------------------
// Scan phase A: per-block sums of deg.
// ---------------------------------------------------------------------------
__global__ __launch_bounds__(256) void scan_blocksums(
    const int* __restrict__ deg, int* __restrict__ part, int N)
{
    int tid = threadIdx.x;
    int idx = blockIdx.x * SCAN_CHUNK + tid * 4;
    int s = 0;
    if (idx < N) {
        int4 v = *(const int4*)(deg + idx);
        s = v.x + v.y + v.z + v.w;
    }
    #pragma unroll
    for (int off = 32; off > 0; off >>= 1) s += __shfl_down(s, off);
    __shared__ int ws[4];
    int wave = tid >> 6, lane = tid & 63;
    if (lane == 0) ws[wave] = s;
    __syncthreads();
    if (tid == 0) part[blockIdx.x] = ws[0] + ws[1] + ws[2] + ws[3];
}

// ---------------------------------------------------------------------------
// Scan phase B: one wave scans the NB partials in-place (-> exclusive).
// ---------------------------------------------------------------------------
__global__ __launch_bounds__(64) void scan_partials(int* part, int NB)
{
    int lane = threadIdx.x;
    int carry = 0;
    for (int base = 0; base < NB; base += 64) {
        int i = base + lane;
        int v = (i < NB) ? part[i] : 0;
        int sc = v;
        #pragma unroll
        for (int off = 1; off < 64; off <<= 1) {
            int t = __shfl_up(sc, off);
            if (lane >= off) sc += t;
        }
        if (i < NB) part[i] = carry + sc - v;
        carry += __shfl(sc, 63);
    }
}

// ---------------------------------------------------------------------------
// Scan phase C: block-level exclusive scan + block offset -> rs.
// ---------------------------------------------------------------------------
__global__ __launch_bounds__(256) void scan_final(
    const int* __restrict__ deg, const int* __restrict__ part,
    int* __restrict__ rs, int N)
{
    int tid = threadIdx.x;
    int idx = blockIdx.x * SCAN_CHUNK + tid * 4;
    int4 v = make_int4(0, 0, 0, 0);
    if (idx < N) v = *(const int4*)(deg + idx);
    int s = v.x + v.y + v.z + v.w;

    int lane = tid & 63, wave = tid >> 6;
    int sc = s;
    #pragma unroll
    for (int off = 1; off < 64; off <<= 1) {
        int t = __shfl_up(sc, off);
        if (lane >= off) sc += t;
    }
    __shared__ int ws[4];
    if (lane == 63) ws[wave] = sc;
    __syncthreads();
    int woff = 0;
    #pragma unroll
    for (int w = 0; w < 4; ++w) if (w < wave) woff += ws[w];

    if (idx < N) {
        int ex = part[blockIdx.x] + woff + (sc - s);
        int4 o;
        o.x = ex;
        o.y = o.x + v.x;
        o.z = o.y + v.y;
        o.w = o.z + v.z;
        *(int4*)(rs + idx) = o;
    }
}

// ---------------------------------------------------------------------------
// CSR step 3: fill, XCD-sliced + non-temporal ei stream.  The slice's csr
// write region (~800 KB) then stays L2-resident until lines are full ->
// full-line writebacks instead of the 73 MB partial-line drain.
// After: rs[n] == inclusive prefix.
// ---------------------------------------------------------------------------
__global__ __launch_bounds__(256) void fill_kernel(
    const int* __restrict__ ei, int* __restrict__ rs,
    int* __restrict__ csr, int E, int sliceSize)
{
    int slice = blockIdx.x & (NSLICE - 1);
    int gid = (blockIdx.x >> 3) * 256 + threadIdx.x;
    if (gid >= E) return;
    int d = __builtin_nontemporal_load(&ei[E + gid]);
    int lo = slice * sliceSize;
    if (d < lo || d >= lo + sliceSize) return;
    int s = __builtin_nontemporal_load(&ei[gid]);
    int pos = atomicAdd(&rs[d], 1);
    csr[pos] = s;
}

// ---------------------------------------------------------------------------
// Gather + GIN combine: acc = sum_j xb[src_j]; u = (1+eps)*x[node] + acc,
// written bf16 to ub.  csr stream read non-temporally (single-use) so it
// doesn't evict xb rows from L2.
// ---------------------------------------------------------------------------
__global__ __launch_bounds__(256) void gather_kernel(
    const unsigned short* __restrict__ xb, const float* __restrict__ x,
    const float* __restrict__ epsp, const int* __restrict__ rs,
    const int* __restrict__ csr, unsigned short* __restrict__ ub, int N)
{
    int sub  = threadIdx.x >> 5;
    int lane = threadIdx.x & 31;
    int node = blockIdx.x * 8 + sub;
    if (node >= N) return;

    int start = (node == 0) ? 0 : rs[node - 1];
    int end   = rs[node];

    float4 acc = make_float4(0.f, 0.f, 0.f, 0.f);
    union { unsigned int u; float f; } c;
    #define BF2F(us) (c.u = ((unsigned int)(us)) << 16, c.f)

    int j = start;
    for (; j + 3 < end; j += 4) {
        int s0 = __builtin_nontemporal_load(&csr[j]);
        int s1 = __builtin_nontemporal_load(&csr[j + 1]);
        int s2 = __builtin_nontemporal_load(&csr[j + 2]);
        int s3 = __builtin_nontemporal_load(&csr[j + 3]);
        ushort4 v0 = ((const ushort4*)(xb + (size_t)s0 * D))[lane];
        ushort4 v1 = ((const ushort4*)(xb + (size_t)s1 * D))[lane];
        ushort4 v2 = ((const ushort4*)(xb + (size_t)s2 * D))[lane];
        ushort4 v3 = ((const ushort4*)(xb + (size_t)s3 * D))[lane];
        acc.x += (BF2F(v0.x) + BF2F(v1.x)) + (BF2F(v2.x) + BF2F(v3.x));
        acc.y += (BF2F(v0.y) + BF2F(v1.y)) + (BF2F(v2.y) + BF2F(v3.y));
        acc.z += (BF2F(v0.z) + BF2F(v1.z)) + (BF2F(v2.z) + BF2F(v3.z));
        acc.w += (BF2F(v0.w) + BF2F(v1.w)) + (BF2F(v2.w) + BF2F(v3.w));
    }
    for (; j < end; ++j) {
        int s0 = __builtin_nontemporal_load(&csr[j]);
        ushort4 v0 = ((const ushort4*)(xb + (size_t)s0 * D))[lane];
        acc.x += BF2F(v0.x); acc.y += BF2F(v0.y);
        acc.z += BF2F(v0.z); acc.w += BF2F(v0.w);
    }
    #undef BF2F

    // GIN combine: u = (1+eps)*x + agg   (x read fp32 for accuracy)
    float ep1 = 1.0f + epsp[0];
    float4 xr = ((const float4*)(x + (size_t)node * D))[lane];
    acc.x = fmaf(ep1, xr.x, acc.x);
    acc.y = fmaf(ep1, xr.y, acc.y);
    acc.z = fmaf(ep1, xr.z, acc.z);
    acc.w = fmaf(ep1, xr.w, acc.w);
    ushort4 o;
    o.x = f2bf(acc.x); o.y = f2bf(acc.y); o.z = f2bf(acc.z); o.w = f2bf(acc.w);
    ((ushort4*)(ub + (size_t)node * D))[lane] = o;
}

// ---------------------------------------------------------------------------
// bf16 MFMA GEMM (unchanged, round-6 verified): 64 rows/block, 4 waves,
// mfma_f32_16x16x32_bf16, Wt pre-transposed, LDS pitch 136 (2-way = free).
// ---------------------------------------------------------------------------
__global__ __launch_bounds__(256, 2) void mfma_gemm(
    const unsigned short* __restrict__ in, const unsigned short* __restrict__ Wt,
    const float* __restrict__ bias, void* __restrict__ outp,
    int N, int relu_bf16)
{
    __shared__ unsigned short Wl[128 * LDSPITCH];  // 34816 B
    __shared__ unsigned short Al[64 * LDSPITCH];   // 17408 B

    int tid = threadIdx.x;
    int row0 = blockIdx.x * 64;

    for (int i = tid; i < 128 * 16; i += 256) {            // stage Wt
        int r = i >> 4, cc = i & 15;
        ((int4*)(Wl + r * LDSPITCH))[cc] = ((const int4*)(Wt + r * 128))[cc];
    }
    for (int i = tid; i < 64 * 16; i += 256) {             // stage A (zero-pad)
        int r = i >> 4, cc = i & 15;
        int4 v = make_int4(0, 0, 0, 0);
        if (row0 + r < N) v = ((const int4*)(in + (size_t)(row0 + r) * 128))[cc];
        ((int4*)(Al + r * LDSPITCH))[cc] = v;
    }
    __syncthreads();

    int wave = tid >> 6, lane = tid & 63;
    int l16 = lane & 15, lq = lane >> 4;

    f32x4 acc[8];
    #pragma unroll
    for (int t = 0; t < 8; ++t) acc[t] = (f32x4){0.f, 0.f, 0.f, 0.f};

    int arow = wave * 16 + l16;
    #pragma unroll
    for (int kk = 0; kk < 4; ++kk) {
        int k0 = kk * 32 + lq * 8;
        bf16x8 a = *(const bf16x8*)(Al + arow * LDSPITCH + k0);
        #pragma unroll
        for (int t = 0; t < 8; ++t) {
            bf16x8 b = *(const bf16x8*)(Wl + (t * 16 + l16) * LDSPITCH + k0);
            acc[t] = __builtin_amdgcn_mfma_f32_16x16x32_bf16(a, b, acc[t], 0, 0, 0);
        }
    }

    #pragma unroll
    for (int t = 0; t < 8; ++t) {
        int col = t * 16 + l16;
        float bv = bias[col];
        #pragma unroll
        for (int r = 0; r < 4; ++r) {
            int row = row0 + wave * 16 + lq * 4 + r;
            if (row >= N) continue;
            float v = acc[t][r] + bv;
            if (relu_bf16) {
                v = fmaxf(v, 0.0f);
                ((unsigned short*)outp)[(size_t)row * 128 + col] = f2bf(v);
            } else {
                ((float*)outp)[(size_t)row * 128 + col] = v;
            }
        }
    }
}

extern "C" void kernel_launch(void* const* d_in, const int* in_sizes, int n_in,
                              void* d_out, int out_size, void* d_ws, size_t ws_size,
                              hipStream_t stream) {
    const float* x   = (const float*)d_in[0];
    const int*   ei  = (const int*)d_in[1];    // edge_index [2][E]
    const float* eps = (const float*)d_in[2];
    const float* W1  = (const float*)d_in[3];
    const float* b1  = (const float*)d_in[4];
    const float* W2  = (const float*)d_in[5];
    const float* b2  = (const float*)d_in[6];
    float* out = (float*)d_out;

    int E = in_sizes[1] / 2;                   // 1,600,000
    int N = in_sizes[0] / D;                   // 100,000
    int sliceSize = (N + NSLICE - 1) / NSLICE; // 12,500

    // workspace layout (bytes):
    //   [0, 400000)              deg  int[N]
    //   [400000, 800000)         rs   int[N]
    //   [800000, 801024)         part int[NB]
    //   [801024, 7201024)        csr  int[E]
    //   [7201024, 32801024)      xb   bf16[N*D]  -- reused as hb after gather
    //   [32801024, 58401024)     ub   bf16[N*D]
    //   [58401024, 58433792)     W1t  bf16[128*128]
    //   [58433792, 58466560)     W2t  bf16[128*128]
    char* ws = (char*)d_ws;
    int* deg   = (int*)(ws);
    int* rs    = (int*)(ws + 400000);
    int* part  = (int*)(ws + 800000);
    int* csr   = (int*)(ws + 801024);
    unsigned short* xb  = (unsigned short*)(ws + 7201024);
    unsigned short* hb  = xb;   // safe: xb dead after gather, stream-ordered
    unsigned short* ub  = (unsigned short*)(ws + 32801024);
    unsigned short* W1t = (unsigned short*)(ws + 58401024);
    unsigned short* W2t = (unsigned short*)(ws + 58433792);

    hipMemsetAsync(deg, 0, (size_t)N * sizeof(int), stream);

    int total4 = N * D / 4;
    convert_kernel<<<(total4 + 255) / 256, 256, 0, stream>>>(x, xb, total4);
    convw_kernel<<<64, 256, 0, stream>>>(W1, W1t);
    convw_kernel<<<64, 256, 0, stream>>>(W2, W2t);

    int eblocks = (E + 255) / 256;
    hist_kernel<<<eblocks * NSLICE, 256, 0, stream>>>(ei, deg, E, sliceSize);

    int NB = (N + SCAN_CHUNK - 1) / SCAN_CHUNK;
    scan_blocksums<<<NB, 256, 0, stream>>>(deg, part, N);
    scan_partials<<<1, 64, 0, stream>>>(part, NB);
    scan_final<<<NB, 256, 0, stream>>>(deg, part, rs, N);

    fill_kernel<<<eblocks * NSLICE, 256, 0, stream>>>(ei, rs, csr, E, sliceSize);

    gather_kernel<<<(N + 7) / 8, 256, 0, stream>>>(xb, x, eps, rs, csr, ub, N);

    int gemm_blocks = (N + 63) / 64;           // 1563
    mfma_gemm<<<gemm_blocks, 256, 0, stream>>>(ub, W1t, b1, (void*)hb, N, 1);
    mfma_gemm<<<gemm_blocks, 256, 0, stream>>>(hb, W2t, b2, (void*)out, N, 0);
}

// Round 8
// 362.004 us; speedup vs baseline: 1.0908x; 1.0908x over previous
//
#include <hip/hip_runtime.h>

#define D 128
#define SCAN_CHUNK 1024   // elements per scan block (256 threads x int4)
#define NSLICE 8          // XCD count: blockIdx%8 -> XCD (perf heuristic)
#define LDSPITCH 136      // ushorts/row: 128+8 pad (272B = 68 words, 68%32=4 -> 2-way=free)

typedef __attribute__((ext_vector_type(8))) short bf16x8;   // 8 bf16 = 4 VGPR
typedef __attribute__((ext_vector_type(4))) float f32x4;    // MFMA acc

__device__ __forceinline__ unsigned short f2bf(float f) {   // fp32 -> bf16 RNE
    union { float f; unsigned int u; } c; c.f = f;
    return (unsigned short)((c.u + 0x7FFFu + ((c.u >> 16) & 1u)) >> 16);
}

// ---------------------------------------------------------------------------
// x (fp32) -> xb (bf16) for the gather.
// ---------------------------------------------------------------------------
__global__ __launch_bounds__(256) void convert_kernel(
    const float* __restrict__ x, unsigned short* __restrict__ xb, int total4)
{
    int gid = blockIdx.x * 256 + threadIdx.x;
    if (gid >= total4) return;
    float4 v = ((const float4*)x)[gid];
    ushort4 o;
    o.x = f2bf(v.x); o.y = f2bf(v.y); o.z = f2bf(v.z); o.w = f2bf(v.w);
    ((ushort4*)xb)[gid] = o;
}

// ---------------------------------------------------------------------------
// W [k][n] fp32 -> Wt [n][k] bf16 (transposed so B-frags are 16B-contiguous).
// ---------------------------------------------------------------------------
__global__ __launch_bounds__(256) void convw_kernel(
    const float* __restrict__ W, unsigned short* __restrict__ Wt)
{
    int gid = blockIdx.x * 256 + threadIdx.x;   // 0..16383
    int n = gid >> 7, k = gid & 127;
    Wt[n * 128 + k] = f2bf(W[k * 128 + n]);
}

// ---------------------------------------------------------------------------
// CSR step 1: degree histogram, XCD-sliced, nt on the zero-reuse ei stream.
// ---------------------------------------------------------------------------
__global__ __launch_bounds__(256) void hist_kernel(
    const int* __restrict__ ei, int* __restrict__ deg, int E, int sliceSize)
{
    int slice = blockIdx.x & (NSLICE - 1);
    int gid = (blockIdx.x >> 3) * 256 + threadIdx.x;
    if (gid >= E) return;
    int d = __builtin_nontemporal_load(&ei[E + gid]);
    int lo = slice * sliceSize;
    if (d < lo || d >= lo + sliceSize) return;
    atomicAdd(&deg[d], 1);
}

// ---------------------------------------------------------------------------
// Scan phase A: per-block sums of deg.
// ---------------------------------------------------------------------------
__global__ __launch_bounds__(256) void scan_blocksums(
    const int* __restrict__ deg, int* __restrict__ part, int N)
{
    int tid = threadIdx.x;
    int idx = blockIdx.x * SCAN_CHUNK + tid * 4;
    int s = 0;
    if (idx < N) {
        int4 v = *(const int4*)(deg + idx);
        s = v.x + v.y + v.z + v.w;
    }
    #pragma unroll
    for (int off = 32; off > 0; off >>= 1) s += __shfl_down(s, off);
    __shared__ int ws[4];
    int wave = tid >> 6, lane = tid & 63;
    if (lane == 0) ws[wave] = s;
    __syncthreads();
    if (tid == 0) part[blockIdx.x] = ws[0] + ws[1] + ws[2] + ws[3];
}

// ---------------------------------------------------------------------------
// Scan phase B: one wave scans the NB partials in-place (-> exclusive).
// ---------------------------------------------------------------------------
__global__ __launch_bounds__(64) void scan_partials(int* part, int NB)
{
    int lane = threadIdx.x;
    int carry = 0;
    for (int base = 0; base < NB; base += 64) {
        int i = base + lane;
        int v = (i < NB) ? part[i] : 0;
        int sc = v;
        #pragma unroll
        for (int off = 1; off < 64; off <<= 1) {
            int t = __shfl_up(sc, off);
            if (lane >= off) sc += t;
        }
        if (i < NB) part[i] = carry + sc - v;
        carry += __shfl(sc, 63);
    }
}

// ---------------------------------------------------------------------------
// Scan phase C: block-level exclusive scan + block offset -> rs.
// ---------------------------------------------------------------------------
__global__ __launch_bounds__(256) void scan_final(
    const int* __restrict__ deg, const int* __restrict__ part,
    int* __restrict__ rs, int N)
{
    int tid = threadIdx.x;
    int idx = blockIdx.x * SCAN_CHUNK + tid * 4;
    int4 v = make_int4(0, 0, 0, 0);
    if (idx < N) v = *(const int4*)(deg + idx);
    int s = v.x + v.y + v.z + v.w;

    int lane = tid & 63, wave = tid >> 6;
    int sc = s;
    #pragma unroll
    for (int off = 1; off < 64; off <<= 1) {
        int t = __shfl_up(sc, off);
        if (lane >= off) sc += t;
    }
    __shared__ int ws[4];
    if (lane == 63) ws[wave] = sc;
    __syncthreads();
    int woff = 0;
    #pragma unroll
    for (int w = 0; w < 4; ++w) if (w < wave) woff += ws[w];

    if (idx < N) {
        int ex = part[blockIdx.x] + woff + (sc - s);
        int4 o;
        o.x = ex;
        o.y = o.x + v.x;
        o.z = o.y + v.y;
        o.w = o.z + v.z;
        *(int4*)(rs + idx) = o;
    }
}

// ---------------------------------------------------------------------------
// CSR step 3: fill, XCD-sliced, nt on the zero-reuse ei stream.
// After: rs[n] == inclusive prefix.
// ---------------------------------------------------------------------------
__global__ __launch_bounds__(256) void fill_kernel(
    const int* __restrict__ ei, int* __restrict__ rs,
    int* __restrict__ csr, int E, int sliceSize)
{
    int slice = blockIdx.x & (NSLICE - 1);
    int gid = (blockIdx.x >> 3) * 256 + threadIdx.x;
    if (gid >= E) return;
    int d = __builtin_nontemporal_load(&ei[E + gid]);
    int lo = slice * sliceSize;
    if (d < lo || d >= lo + sliceSize) return;
    int s = __builtin_nontemporal_load(&ei[gid]);
    int pos = atomicAdd(&rs[d], 1);
    csr[pos] = s;
}

// ---------------------------------------------------------------------------
// Gather + GIN combine: acc = sum_j xb[src_j]; u = (1+eps)*xb[node] + acc,
// written bf16 to ub.  csr via REGULAR loads (4x intra-line reuse — the
// round-7 nt here was a regression).  32 lanes/node, ushort4/lane.
// ---------------------------------------------------------------------------
__global__ __launch_bounds__(256) void gather_kernel(
    const unsigned short* __restrict__ xb, const float* __restrict__ epsp,
    const int* __restrict__ rs, const int* __restrict__ csr,
    unsigned short* __restrict__ ub, int N)
{
    int sub  = threadIdx.x >> 5;
    int lane = threadIdx.x & 31;
    int node = blockIdx.x * 8 + sub;
    if (node >= N) return;

    int start = (node == 0) ? 0 : rs[node - 1];
    int end   = rs[node];

    float4 acc = make_float4(0.f, 0.f, 0.f, 0.f);
    union { unsigned int u; float f; } c;
    #define BF2F(us) (c.u = ((unsigned int)(us)) << 16, c.f)

    int j = start;
    for (; j + 3 < end; j += 4) {
        int s0 = csr[j], s1 = csr[j + 1], s2 = csr[j + 2], s3 = csr[j + 3];
        ushort4 v0 = ((const ushort4*)(xb + (size_t)s0 * D))[lane];
        ushort4 v1 = ((const ushort4*)(xb + (size_t)s1 * D))[lane];
        ushort4 v2 = ((const ushort4*)(xb + (size_t)s2 * D))[lane];
        ushort4 v3 = ((const ushort4*)(xb + (size_t)s3 * D))[lane];
        acc.x += (BF2F(v0.x) + BF2F(v1.x)) + (BF2F(v2.x) + BF2F(v3.x));
        acc.y += (BF2F(v0.y) + BF2F(v1.y)) + (BF2F(v2.y) + BF2F(v3.y));
        acc.z += (BF2F(v0.z) + BF2F(v1.z)) + (BF2F(v2.z) + BF2F(v3.z));
        acc.w += (BF2F(v0.w) + BF2F(v1.w)) + (BF2F(v2.w) + BF2F(v3.w));
    }
    for (; j < end; ++j) {
        ushort4 v0 = ((const ushort4*)(xb + (size_t)csr[j] * D))[lane];
        acc.x += BF2F(v0.x); acc.y += BF2F(v0.y);
        acc.z += BF2F(v0.z); acc.w += BF2F(v0.w);
    }

    // GIN combine: u = (1+eps)*xb[node] + agg  (bf16 self-term: err ~2^-9 rel)
    float ep1 = 1.0f + epsp[0];
    ushort4 xr = ((const ushort4*)(xb + (size_t)node * D))[lane];
    acc.x = fmaf(ep1, BF2F(xr.x), acc.x);
    acc.y = fmaf(ep1, BF2F(xr.y), acc.y);
    acc.z = fmaf(ep1, BF2F(xr.z), acc.z);
    acc.w = fmaf(ep1, BF2F(xr.w), acc.w);
    #undef BF2F
    ushort4 o;
    o.x = f2bf(acc.x); o.y = f2bf(acc.y); o.z = f2bf(acc.z); o.w = f2bf(acc.w);
    ((ushort4*)(ub + (size_t)node * D))[lane] = o;
}

// ---------------------------------------------------------------------------
// Fused 2-layer MLP (bf16 MFMA): y = relu(u@W1+b1)@W2+b2, one dispatch.
// 64 rows/block, 4 waves, mfma_f32_16x16x32_bf16, 8 col-tiles/wave.
// Phase 1: Wl=W1t, Al=u  -> acc=h.  Barrier.  Restage Wl=W2t, write
// relu(h) bf16 into Al (C-layout row=lq*4+r col=t*16+l16 -> A-layout rows;
// each wave writes only its own 16 rows).  Barrier.  Phase 2 -> fp32 out.
// Saves the 51.2 MB hb round-trip and one full staging pass.
// LDS 52.2 KB -> 3 blocks/CU.
// ---------------------------------------------------------------------------
__global__ __launch_bounds__(256, 2) void mlp_fused(
    const unsigned short* __restrict__ in,
    const unsigned short* __restrict__ W1t, const float* __restrict__ b1,
    const unsigned short* __restrict__ W2t, const float* __restrict__ b2,
    float* __restrict__ out, int N)
{
    __shared__ unsigned short Wl[128 * LDSPITCH];  // 34816 B
    __shared__ unsigned short Al[64 * LDSPITCH];   // 17408 B

    int tid = threadIdx.x;
    int row0 = blockIdx.x * 64;
    int wave = tid >> 6, lane = tid & 63;
    int l16 = lane & 15, lq = lane >> 4;

    for (int i = tid; i < 128 * 16; i += 256) {            // stage W1t
        int r = i >> 4, cc = i & 15;
        ((int4*)(Wl + r * LDSPITCH))[cc] = ((const int4*)(W1t + r * 128))[cc];
    }
    for (int i = tid; i < 64 * 16; i += 256) {             // stage u (zero-pad)
        int r = i >> 4, cc = i & 15;
        int4 v = make_int4(0, 0, 0, 0);
        if (row0 + r < N) v = ((const int4*)(in + (size_t)(row0 + r) * 128))[cc];
        ((int4*)(Al + r * LDSPITCH))[cc] = v;
    }
    __syncthreads();

    f32x4 acc[8];
    #pragma unroll
    for (int t = 0; t < 8; ++t) acc[t] = (f32x4){0.f, 0.f, 0.f, 0.f};

    int arow = wave * 16 + l16;
    #pragma unroll
    for (int kk = 0; kk < 4; ++kk) {
        int k0 = kk * 32 + lq * 8;
        bf16x8 a = *(const bf16x8*)(Al + arow * LDSPITCH + k0);
        #pragma unroll
        for (int t = 0; t < 8; ++t) {
            bf16x8 b = *(const bf16x8*)(Wl + (t * 16 + l16) * LDSPITCH + k0);
            acc[t] = __builtin_amdgcn_mfma_f32_16x16x32_bf16(a, b, acc[t], 0, 0, 0);
        }
    }
    __syncthreads();   // all Wl/Al reads of phase 1 done

    // restage Wl with W2t (cross-wave, tid-strided)
    for (int i = tid; i < 128 * 16; i += 256) {
        int r = i >> 4, cc = i & 15;
        ((int4*)(Wl + r * LDSPITCH))[cc] = ((const int4*)(W2t + r * 128))[cc];
    }
    // write h = relu(acc + b1) bf16 into Al (each wave writes its own rows)
    #pragma unroll
    for (int t = 0; t < 8; ++t) {
        int col = t * 16 + l16;
        float bv = b1[col];
        #pragma unroll
        for (int r = 0; r < 4; ++r) {
            int row = wave * 16 + lq * 4 + r;   // block-local
            float v = fmaxf(acc[t][r] + bv, 0.0f);
            Al[row * LDSPITCH + col] = f2bf(v);
        }
    }
    __syncthreads();

    #pragma unroll
    for (int t = 0; t < 8; ++t) acc[t] = (f32x4){0.f, 0.f, 0.f, 0.f};
    #pragma unroll
    for (int kk = 0; kk < 4; ++kk) {
        int k0 = kk * 32 + lq * 8;
        bf16x8 a = *(const bf16x8*)(Al + arow * LDSPITCH + k0);
        #pragma unroll
        for (int t = 0; t < 8; ++t) {
            bf16x8 b = *(const bf16x8*)(Wl + (t * 16 + l16) * LDSPITCH + k0);
            acc[t] = __builtin_amdgcn_mfma_f32_16x16x32_bf16(a, b, acc[t], 0, 0, 0);
        }
    }

    #pragma unroll
    for (int t = 0; t < 8; ++t) {
        int col = t * 16 + l16;
        float bv = b2[col];
        #pragma unroll
        for (int r = 0; r < 4; ++r) {
            int row = row0 + wave * 16 + lq * 4 + r;
            if (row >= N) continue;
            out[(size_t)row * 128 + col] = acc[t][r] + bv;
        }
    }
}

extern "C" void kernel_launch(void* const* d_in, const int* in_sizes, int n_in,
                              void* d_out, int out_size, void* d_ws, size_t ws_size,
                              hipStream_t stream) {
    const float* x   = (const float*)d_in[0];
    const int*   ei  = (const int*)d_in[1];    // edge_index [2][E]
    const float* eps = (const float*)d_in[2];
    const float* W1  = (const float*)d_in[3];
    const float* b1  = (const float*)d_in[4];
    const float* W2  = (const float*)d_in[5];
    const float* b2  = (const float*)d_in[6];
    float* out = (float*)d_out;

    int E = in_sizes[1] / 2;                   // 1,600,000
    int N = in_sizes[0] / D;                   // 100,000
    int sliceSize = (N + NSLICE - 1) / NSLICE; // 12,500

    // workspace layout (bytes):
    //   [0, 400000)              deg  int[N]
    //   [400000, 800000)         rs   int[N]
    //   [800000, 801024)         part int[NB]
    //   [801024, 7201024)        csr  int[E]
    //   [7201024, 32801024)      xb   bf16[N*D]
    //   [32801024, 58401024)     ub   bf16[N*D]
    //   [58401024, 58433792)     W1t  bf16[128*128]
    //   [58433792, 58466560)     W2t  bf16[128*128]
    char* ws = (char*)d_ws;
    int* deg   = (int*)(ws);
    int* rs    = (int*)(ws + 400000);
    int* part  = (int*)(ws + 800000);
    int* csr   = (int*)(ws + 801024);
    unsigned short* xb  = (unsigned short*)(ws + 7201024);
    unsigned short* ub  = (unsigned short*)(ws + 32801024);
    unsigned short* W1t = (unsigned short*)(ws + 58401024);
    unsigned short* W2t = (unsigned short*)(ws + 58433792);

    hipMemsetAsync(deg, 0, (size_t)N * sizeof(int), stream);

    int total4 = N * D / 4;
    convert_kernel<<<(total4 + 255) / 256, 256, 0, stream>>>(x, xb, total4);
    convw_kernel<<<64, 256, 0, stream>>>(W1, W1t);
    convw_kernel<<<64, 256, 0, stream>>>(W2, W2t);

    int eblocks = (E + 255) / 256;
    hist_kernel<<<eblocks * NSLICE, 256, 0, stream>>>(ei, deg, E, sliceSize);

    int NB = (N + SCAN_CHUNK - 1) / SCAN_CHUNK;
    scan_blocksums<<<NB, 256, 0, stream>>>(deg, part, N);
    scan_partials<<<1, 64, 0, stream>>>(part, NB);
    scan_final<<<NB, 256, 0, stream>>>(deg, part, rs, N);

    fill_kernel<<<eblocks * NSLICE, 256, 0, stream>>>(ei, rs, csr, E, sliceSize);

    gather_kernel<<<(N + 7) / 8, 256, 0, stream>>>(xb, eps, rs, csr, ub, N);

    int gemm_blocks = (N + 63) / 64;           // 1563
    mlp_fused<<<gemm_blocks, 256, 0, stream>>>(ub, W1t, b1, W2t, b2, out, N);
}